// Round 2
// baseline (1311.274 us; speedup 1.0000x reference)
//
#include <hip/hip_runtime.h>

#define NN 100000
#define EE 1700000
#define F1 256
#define NH 8
#define HF 64
#define C1 512
#define C2 40
#define EPS 1e-6f

// ---- ws layout (bytes) ----  total ~236 MB
#define OF_PF1   ((size_t)0)                       // N*512*2 bf16 (ft1 -> pf1 in place)
#define OF_HCAT  (OF_PF1  + 102400000ULL)          // N*512*2 bf16
#define OF_FT2   (OF_HCAT + 102400000ULL)          // N*40*4 f32 (ft2 -> pf2 in place)
#define OF_EL1   (OF_FT2  + 16000000ULL)           // N*8*4
#define OF_ER1   (OF_EL1  + 3200000ULL)
#define OF_EL2   (OF_ER1  + 3200000ULL)            // N*4
#define OF_ER2   (OF_EL2  + 400000ULL)
#define OF_DEG   (OF_ER2  + 400000ULL)             // N*4
#define OF_OFFS  (OF_DEG  + 400000ULL)             // (N+1)*4 padded
#define OF_CUR   (OF_OFFS + 400128ULL)             // N*4
#define OF_SRCC  (OF_CUR  + 400000ULL)             // E*4
#define OF_BSUM  (OF_SRCC + 6800000ULL)            // 2048
#define OF_BOFF  (OF_BSUM + 2048ULL)               // 2048
#define OF_PRM   (OF_BOFF + 2048ULL)               // params block (~136B)

// params block: [0..7] minkey1(u32), [8] minkey2(u32), [16..23] pe1, [24..31] ipe1, [32] pe2, [33] ipe2

__device__ __forceinline__ unsigned f2key(float f){
  unsigned u = __float_as_uint(f);
  return (u & 0x80000000u) ? ~u : (u | 0x80000000u);
}
__device__ __forceinline__ float key2f(unsigned k){
  unsigned u = (k & 0x80000000u) ? (k & 0x7FFFFFFFu) : ~k;
  return __uint_as_float(u);
}
__device__ __forceinline__ unsigned short f2b(float f){  // f32 -> bf16 RNE
  unsigned u = __float_as_uint(f);
  unsigned r = u + 0x7FFFu + ((u >> 16) & 1u);
  return (unsigned short)(r >> 16);
}
__device__ __forceinline__ float b2f(unsigned short b){
  return __uint_as_float(((unsigned)b) << 16);
}
__device__ __forceinline__ unsigned pk2(float lo, float hi){
  return (unsigned)f2b(lo) | ((unsigned)f2b(hi) << 16);
}
__device__ __forceinline__ float leaky(float e){ return e >= 0.f ? e : 0.2f*e; }

// ---------------- init ----------------
__global__ void k_init(const float* __restrict__ p1, const float* __restrict__ p2, unsigned* __restrict__ prm){
  int t = threadIdx.x;
  float* prf = (float*)prm;
  if (t < 8){
    prm[t] = 0xFFFFFFFFu;
    float pe = 1.f/(1.f + __expf(-p1[t])) + 1.0f;
    prf[16 + t] = pe;
    prf[24 + t] = 1.f/pe;
  }
  if (t == 0){
    prm[8] = 0xFFFFFFFFu;
    float pe = 1.f/(1.f + __expf(-p2[0])) + 1.0f;
    prf[32] = pe;
    prf[33] = 1.f/pe;
  }
}

__global__ void k_zero_deg(int* __restrict__ deg){
  int i = blockIdx.x*256 + threadIdx.x;
  if (i < NN) deg[i] = 0;
}

// ---------------- GEMM1: ft1 = x @ W1^T (bf16 out), + per-head global min over rounded values ----------------
#define G1_BM 128
#define G1_BN 128
#define G1_BK 16
__global__ __launch_bounds__(256) void k_gemm1(const float* __restrict__ x, const float* __restrict__ W,
                                               unsigned short* __restrict__ ft1b, unsigned* __restrict__ prm){
  __shared__ float As[G1_BK][G1_BM];
  __shared__ float Bs[G1_BK][G1_BN];
  __shared__ unsigned mk[2];
  int t = threadIdx.x;
  int tx = t & 15, ty = t >> 4;
  int rt = blockIdx.x * G1_BM;
  int ct = blockIdx.y * G1_BN;
  float acc[8][8];
  #pragma unroll
  for (int i=0;i<8;i++)
    #pragma unroll
    for (int j=0;j<8;j++) acc[i][j]=0.f;

  for (int kt = 0; kt < F1; kt += G1_BK){
    #pragma unroll
    for (int i=0;i<2;i++){
      int id = t*2 + i; int row = id >> 2; int c4 = (id & 3)*4;
      int gr = rt + row;
      float4 v = make_float4(0.f,0.f,0.f,0.f);
      if (gr < NN) v = *(const float4*)&x[(size_t)gr*F1 + kt + c4];
      As[c4+0][row]=v.x; As[c4+1][row]=v.y; As[c4+2][row]=v.z; As[c4+3][row]=v.w;
    }
    #pragma unroll
    for (int i=0;i<2;i++){
      int id = t*2 + i; int row = id >> 2; int c4 = (id & 3)*4;
      float4 v = *(const float4*)&W[(size_t)(ct+row)*F1 + kt + c4];
      Bs[c4+0][row]=v.x; Bs[c4+1][row]=v.y; Bs[c4+2][row]=v.z; Bs[c4+3][row]=v.w;
    }
    __syncthreads();
    #pragma unroll
    for (int kk=0; kk<G1_BK; ++kk){
      float4 a0 = *(float4*)&As[kk][ty*4];
      float4 a1 = *(float4*)&As[kk][ty*4+64];
      float4 b0 = *(float4*)&Bs[kk][tx*4];
      float4 b1 = *(float4*)&Bs[kk][tx*4+64];
      float av[8] = {a0.x,a0.y,a0.z,a0.w,a1.x,a1.y,a1.z,a1.w};
      float bv[8] = {b0.x,b0.y,b0.z,b0.w,b1.x,b1.y,b1.z,b1.w};
      #pragma unroll
      for (int i=0;i<8;i++)
        #pragma unroll
        for (int j=0;j<8;j++) acc[i][j] += av[i]*bv[j];
    }
    __syncthreads();
  }

  unsigned kmin0 = 0xFFFFFFFFu, kmin1 = 0xFFFFFFFFu;
  #pragma unroll
  for (int ri=0; ri<8; ri++){
    int r = rt + (ri>>2)*64 + ty*4 + (ri&3);
    if (r < NN){
      unsigned short u0[4], u1[4];
      #pragma unroll
      for (int j=0;j<4;j++){
        u0[j] = f2b(acc[ri][j]);
        u1[j] = f2b(acc[ri][4+j]);
        kmin0 = min(kmin0, f2key(b2f(u0[j])));
        kmin1 = min(kmin1, f2key(b2f(u1[j])));
      }
      ushort4 s0 = make_ushort4(u0[0],u0[1],u0[2],u0[3]);
      ushort4 s1 = make_ushort4(u1[0],u1[1],u1[2],u1[3]);
      *(ushort4*)&ft1b[(size_t)r*C1 + ct + tx*4]      = s0;
      *(ushort4*)&ft1b[(size_t)r*C1 + ct + 64 + tx*4] = s1;
    }
  }
  if (t < 2) mk[t] = 0xFFFFFFFFu;
  __syncthreads();
  atomicMin(&mk[0], kmin0);
  atomicMin(&mk[1], kmin1);
  __syncthreads();
  if (t < 2) atomicMin(&prm[blockIdx.y*2 + t], mk[t]);
}

// ---------------- CSR build ----------------
__global__ void k_count(const int* __restrict__ dst, int* __restrict__ deg){
  int e = blockIdx.x*256 + threadIdx.x;
  if (e < EE) atomicAdd(&deg[dst[e]], 1);
}
__global__ void k_scan1(const int* __restrict__ deg, int* __restrict__ offs, int* __restrict__ bsum){
  __shared__ int s[256];
  int t = threadIdx.x; int i = blockIdx.x*256 + t;
  int v = (i < NN) ? deg[i] : 0;
  s[t] = v; __syncthreads();
  for (int off=1; off<256; off<<=1){
    int tmp = (t>=off) ? s[t-off] : 0;
    __syncthreads(); s[t] += tmp; __syncthreads();
  }
  if (i < NN) offs[i] = s[t] - v;
  if (t == 255) bsum[blockIdx.x] = s[255];
}
__global__ void k_scan2(int* __restrict__ bsum, int* __restrict__ boff, int nb){
  __shared__ int s[512];
  int t = threadIdx.x;
  int v = (t < nb) ? bsum[t] : 0;
  s[t] = v; __syncthreads();
  for (int off=1; off<512; off<<=1){
    int tmp = (t>=off) ? s[t-off] : 0;
    __syncthreads(); s[t] += tmp; __syncthreads();
  }
  if (t < nb) boff[t] = s[t] - v;
}
__global__ void k_scan3(int* __restrict__ offs, int* __restrict__ cur, const int* __restrict__ boff){
  int i = blockIdx.x*256 + threadIdx.x;
  if (i < NN){
    int v = offs[i] + boff[blockIdx.x];
    offs[i] = v; cur[i] = v;
  }
  if (i == 0) offs[NN] = EE;
}
__global__ void k_fill(const int* __restrict__ src, const int* __restrict__ dst,
                       int* __restrict__ cur, int* __restrict__ srcc){
  int e = blockIdx.x*256 + threadIdx.x;
  if (e < EE){
    int d = dst[e];
    int pos = atomicAdd(&cur[d], 1);
    srcc[pos] = src[e];
  }
}

// ---------------- transform1: el1/er1 + pf1 (in place, bf16) ----------------
__global__ __launch_bounds__(256) void k_transform1(unsigned short* __restrict__ ft1b,
    const float* __restrict__ al1, const float* __restrict__ ar1,
    float* __restrict__ el1, float* __restrict__ er1, const unsigned* __restrict__ prm){
  int lane = threadIdx.x & 63; int w = threadIdx.x >> 6;
  int n = blockIdx.x*4 + w;
  if (n >= NN) return;
  const float* prf = (const float*)prm;
  float vv[8], elp[8], erp[8];
  #pragma unroll
  for (int h=0; h<8; h++){
    vv[h]  = b2f(ft1b[(size_t)n*C1 + h*HF + lane]);
    elp[h] = vv[h]*al1[h*HF + lane];
    erp[h] = vv[h]*ar1[h*HF + lane];
  }
  #pragma unroll
  for (int h=0; h<8; h++){
    #pragma unroll
    for (int off=1; off<64; off<<=1){
      elp[h] += __shfl_xor(elp[h], off);
      erp[h] += __shfl_xor(erp[h], off);
    }
  }
  if (lane == 0){
    #pragma unroll
    for (int h=0; h<8; h++){ el1[(size_t)n*8+h]=elp[h]; er1[(size_t)n*8+h]=erp[h]; }
  }
  #pragma unroll
  for (int h=0; h<8; h++){
    float mu = key2f(prm[h]);
    float pe = prf[16+h];
    float base = vv[h] - mu + EPS;   // >= EPS since mu is min over rounded values
    ft1b[(size_t)n*C1 + h*HF + lane] = f2b(__expf(pe * __logf(base)));
  }
}

// ---------------- layer-1 fused attention + aggregation + elu (bf16 tables) ----------------
__global__ __launch_bounds__(256) void k_agg1(const unsigned short* __restrict__ pf1b,
    const float* __restrict__ el1, const float* __restrict__ er1,
    const int* __restrict__ offs, const int* __restrict__ srcc,
    const float* __restrict__ b1, const unsigned* __restrict__ prm,
    unsigned short* __restrict__ hcatb){
  int lane = threadIdx.x & 63; int w = threadIdx.x >> 6;
  int v = blockIdx.x*4 + w;
  if (v >= NN) return;
  const float* prf = (const float*)prm;
  int h = lane >> 3;
  int s = lane & 7;
  int f0 = (lane & 7)*8;
  int start = offs[v], end = offs[v+1];
  float erh = er1[(size_t)v*8 + h];

  float m = -INFINITY;
  for (int pos = start + s; pos < end; pos += 8){
    int u = srcc[pos];
    float e = leaky(el1[(size_t)u*8 + h] + erh);
    m = fmaxf(m, e);
  }
  m = fmaxf(m, __shfl_xor(m,1)); m = fmaxf(m, __shfl_xor(m,2)); m = fmaxf(m, __shfl_xor(m,4));
  float S = 0.f;
  for (int pos = start + s; pos < end; pos += 8){
    int u = srcc[pos];
    float e = leaky(el1[(size_t)u*8 + h] + erh);
    S += __expf(e - m);
  }
  S += __shfl_xor(S,1); S += __shfl_xor(S,2); S += __shfl_xor(S,4);
  float invS = 1.f / S;

  float acc[8];
  #pragma unroll
  for (int j=0;j<8;j++) acc[j]=0.f;
  for (int pos = start; pos < end; ++pos){
    int u = srcc[pos];
    float e = leaky(el1[(size_t)u*8 + h] + erh);
    float a = __expf(e - m) * invS;
    uint4 q = *(const uint4*)&pf1b[(size_t)u*C1 + h*HF + f0];
    acc[0] += a*b2f((unsigned short)(q.x & 0xFFFFu));
    acc[1] += a*b2f((unsigned short)(q.x >> 16));
    acc[2] += a*b2f((unsigned short)(q.y & 0xFFFFu));
    acc[3] += a*b2f((unsigned short)(q.y >> 16));
    acc[4] += a*b2f((unsigned short)(q.z & 0xFFFFu));
    acc[5] += a*b2f((unsigned short)(q.z >> 16));
    acc[6] += a*b2f((unsigned short)(q.w & 0xFFFFu));
    acc[7] += a*b2f((unsigned short)(q.w >> 16));
  }

  float mu = key2f(prm[h]);
  float ipe = prf[24+h];
  float y[8];
  #pragma unroll
  for (int j=0;j<8;j++){
    float r = __expf(ipe * __logf(acc[j] + EPS)) + mu + b1[h*HF + f0 + j];
    y[j] = (r > 0.f) ? r : (__expf(r) - 1.f);
  }
  uint4 o;
  o.x = pk2(y[0],y[1]); o.y = pk2(y[2],y[3]); o.z = pk2(y[4],y[5]); o.w = pk2(y[6],y[7]);
  *(uint4*)&hcatb[(size_t)v*C1 + h*HF + f0] = o;
}

// ---------------- GEMM2: ft2 = hcat @ W2^T (f32 out), + el2/er2 + global min ----------------
#define G2_BM 64
#define G2_BK 64
__global__ __launch_bounds__(256) void k_gemm2(const unsigned short* __restrict__ hcatb, const float* __restrict__ W2,
    float* __restrict__ ft2, float* __restrict__ el2, float* __restrict__ er2,
    const float* __restrict__ al2, const float* __restrict__ ar2, unsigned* __restrict__ prm){
  __shared__ float As[G2_BK][G2_BM];
  __shared__ float Bs[G2_BK][C2];
  __shared__ float els[64], ers[64];
  __shared__ unsigned mk;
  int t = threadIdx.x;
  int tx = t & 7, ty = t >> 3;
  int rt = blockIdx.x * G2_BM;
  float acc[2][5];
  #pragma unroll
  for (int i=0;i<2;i++)
    #pragma unroll
    for (int j=0;j<5;j++) acc[i][j]=0.f;

  for (int k0=0; k0<C1; k0+=G2_BK){
    #pragma unroll
    for (int i=0;i<2;i++){
      int id = t*2 + i;                 // 0..511
      int row = id >> 3; int c8 = (id & 7)*8;
      int gr = rt + row;
      uint4 q = make_uint4(0,0,0,0);
      if (gr < NN) q = *(const uint4*)&hcatb[(size_t)gr*C1 + k0 + c8];
      As[c8+0][row]=b2f((unsigned short)(q.x & 0xFFFFu));
      As[c8+1][row]=b2f((unsigned short)(q.x >> 16));
      As[c8+2][row]=b2f((unsigned short)(q.y & 0xFFFFu));
      As[c8+3][row]=b2f((unsigned short)(q.y >> 16));
      As[c8+4][row]=b2f((unsigned short)(q.z & 0xFFFFu));
      As[c8+5][row]=b2f((unsigned short)(q.z >> 16));
      As[c8+6][row]=b2f((unsigned short)(q.w & 0xFFFFu));
      As[c8+7][row]=b2f((unsigned short)(q.w >> 16));
    }
    #pragma unroll
    for (int i=0;i<10;i++){
      int id = t + i*256;
      int c = id >> 6, kk = id & 63;
      Bs[kk][c] = W2[(size_t)c*C1 + k0 + kk];
    }
    __syncthreads();
    #pragma unroll
    for (int kk=0; kk<G2_BK; ++kk){
      float2 a = *(float2*)&As[kk][ty*2];
      float b0=Bs[kk][tx*5+0], b1v=Bs[kk][tx*5+1], b2v=Bs[kk][tx*5+2], b3v=Bs[kk][tx*5+3], b4v=Bs[kk][tx*5+4];
      acc[0][0]+=a.x*b0; acc[0][1]+=a.x*b1v; acc[0][2]+=a.x*b2v; acc[0][3]+=a.x*b3v; acc[0][4]+=a.x*b4v;
      acc[1][0]+=a.y*b0; acc[1][1]+=a.y*b1v; acc[1][2]+=a.y*b2v; acc[1][3]+=a.y*b3v; acc[1][4]+=a.y*b4v;
    }
    __syncthreads();
  }

  if (t < 64){ els[t]=0.f; ers[t]=0.f; }
  if (t == 0) mk = 0xFFFFFFFFu;
  __syncthreads();
  unsigned kmin = 0xFFFFFFFFu;
  #pragma unroll
  for (int i=0;i<2;i++){
    int r = rt + ty*2 + i;
    if (r < NN){
      float elp=0.f, erp=0.f;
      #pragma unroll
      for (int j=0;j<5;j++){
        float vv = acc[i][j]; int c = tx*5+j;
        ft2[(size_t)r*C2 + c] = vv;
        elp += vv*al2[c]; erp += vv*ar2[c];
        kmin = min(kmin, f2key(vv));
      }
      atomicAdd(&els[ty*2+i], elp);
      atomicAdd(&ers[ty*2+i], erp);
    }
  }
  atomicMin(&mk, kmin);
  __syncthreads();
  if (t < 64 && rt + t < NN){ el2[rt+t]=els[t]; er2[rt+t]=ers[t]; }
  if (t == 0) atomicMin(&prm[8], mk);
}

// ---------------- transform2: pf2 in place (f32) ----------------
__global__ void k_transform2(float* __restrict__ ft2, const unsigned* __restrict__ prm){
  int i = blockIdx.x*256 + threadIdx.x;
  if (i >= NN*C2) return;
  const float* prf = (const float*)prm;
  float mu = key2f(prm[8]);
  float pe = prf[32];
  float v = ft2[i];
  ft2[i] = __expf(pe * __logf(v - mu + EPS));
}

// ---------------- layer-2 fused attention + aggregation + log_softmax ----------------
__global__ __launch_bounds__(256) void k_agg2(const float* __restrict__ pf2,
    const float* __restrict__ el2, const float* __restrict__ er2,
    const int* __restrict__ offs, const int* __restrict__ srcc,
    const float* __restrict__ b2, const unsigned* __restrict__ prm,
    float* __restrict__ out){
  int lane = threadIdx.x & 63; int w = threadIdx.x >> 6;
  int v = blockIdx.x*4 + w;
  if (v >= NN) return;
  const float* prf = (const float*)prm;
  int start = offs[v], end = offs[v+1];
  float erv = er2[v];

  float m = -INFINITY;
  for (int pos = start + lane; pos < end; pos += 64){
    float e = leaky(el2[srcc[pos]] + erv);
    m = fmaxf(m, e);
  }
  #pragma unroll
  for (int off=1; off<64; off<<=1) m = fmaxf(m, __shfl_xor(m, off));
  float S = 0.f;
  for (int pos = start + lane; pos < end; pos += 64){
    float e = leaky(el2[srcc[pos]] + erv);
    S += __expf(e - m);
  }
  #pragma unroll
  for (int off=1; off<64; off<<=1) S += __shfl_xor(S, off);
  float invS = 1.f / S;

  float acc = 0.f;
  for (int pos = start; pos < end; ++pos){
    int u = srcc[pos];
    float e = leaky(el2[u] + erv);
    float a = __expf(e - m) * invS;
    if (lane < C2) acc += a * pf2[(size_t)u*C2 + lane];
  }

  float y;
  if (lane < C2){
    float mu = key2f(prm[8]);
    y = __expf(prf[33] * __logf(acc + EPS)) + mu + b2[lane];
  } else {
    y = -INFINITY;
  }
  float mx = y;
  #pragma unroll
  for (int off=1; off<64; off<<=1) mx = fmaxf(mx, __shfl_xor(mx, off));
  float se = (lane < C2) ? __expf(y - mx) : 0.f;
  #pragma unroll
  for (int off=1; off<64; off<<=1) se += __shfl_xor(se, off);
  if (lane < C2) out[(size_t)v*C2 + lane] = y - mx - __logf(se);
}

// ---------------- host ----------------
extern "C" void kernel_launch(void* const* d_in, const int* in_sizes, int n_in,
                              void* d_out, int out_size, void* d_ws, size_t ws_size,
                              hipStream_t stream){
  const float* x   = (const float*)d_in[0];
  const int*   src = (const int*)d_in[1];
  const int*   dst = (const int*)d_in[2];
  const float* W1  = (const float*)d_in[3];
  const float* al1 = (const float*)d_in[4];
  const float* ar1 = (const float*)d_in[5];
  const float* b1  = (const float*)d_in[6];
  const float* p1  = (const float*)d_in[7];
  const float* W2  = (const float*)d_in[8];
  const float* al2 = (const float*)d_in[9];
  const float* ar2 = (const float*)d_in[10];
  const float* b2  = (const float*)d_in[11];
  const float* p2  = (const float*)d_in[12];
  float* out = (float*)d_out;
  char* ws = (char*)d_ws;

  unsigned short* pf1b  = (unsigned short*)(ws + OF_PF1);
  unsigned short* hcatb = (unsigned short*)(ws + OF_HCAT);
  float* ft2   = (float*)(ws + OF_FT2);
  float* el1   = (float*)(ws + OF_EL1);
  float* er1   = (float*)(ws + OF_ER1);
  float* el2   = (float*)(ws + OF_EL2);
  float* er2   = (float*)(ws + OF_ER2);
  int*   deg   = (int*)(ws + OF_DEG);
  int*   offs  = (int*)(ws + OF_OFFS);
  int*   cur   = (int*)(ws + OF_CUR);
  int*   srcc  = (int*)(ws + OF_SRCC);
  int*   bsum  = (int*)(ws + OF_BSUM);
  int*   boff  = (int*)(ws + OF_BOFF);
  unsigned* prm = (unsigned*)(ws + OF_PRM);

  const int NB1 = (NN + 255)/256;
  const int NBE = (EE + 255)/256;

  k_init<<<1, 64, 0, stream>>>(p1, p2, prm);
  k_zero_deg<<<NB1, 256, 0, stream>>>(deg);
  k_gemm1<<<dim3((NN + G1_BM - 1)/G1_BM, C1/G1_BN), 256, 0, stream>>>(x, W1, pf1b, prm);
  k_count<<<NBE, 256, 0, stream>>>(dst, deg);
  k_scan1<<<NB1, 256, 0, stream>>>(deg, offs, bsum);
  k_scan2<<<1, 512, 0, stream>>>(bsum, boff, NB1);
  k_scan3<<<NB1, 256, 0, stream>>>(offs, cur, boff);
  k_fill<<<NBE, 256, 0, stream>>>(src, dst, cur, srcc);
  k_transform1<<<NN/4, 256, 0, stream>>>(pf1b, al1, ar1, el1, er1, prm);
  k_agg1<<<NN/4, 256, 0, stream>>>(pf1b, el1, er1, offs, srcc, b1, prm, hcatb);
  k_gemm2<<<(NN + G2_BM - 1)/G2_BM, 256, 0, stream>>>(hcatb, W2, ft2, el2, er2, al2, ar2, prm);
  k_transform2<<<(NN*C2 + 255)/256, 256, 0, stream>>>(ft2, prm);
  k_agg2<<<NN/4, 256, 0, stream>>>(ft2, el2, er2, offs, srcc, b2, prm, out);
}

// Round 3
// 1198.932 us; speedup vs baseline: 1.0937x; 1.0937x over previous
//
#include <hip/hip_runtime.h>

#define NN 100000
#define EE 1700000
#define F1 256
#define NH 8
#define HF 64
#define C1 512
#define C2 40
#define EPS 1e-6f

// ---- ws layout (bytes) ----  total ~236 MB
#define OF_PF1   ((size_t)0)                       // N*512*2 bf16 (ft1 -> pf1 in place)
#define OF_HCAT  (OF_PF1  + 102400000ULL)          // N*512*2 bf16
#define OF_FT2   (OF_HCAT + 102400000ULL)          // N*40*4 f32 (ft2 -> pf2 in place)
#define OF_EL1   (OF_FT2  + 16000000ULL)           // N*8*4
#define OF_ER1   (OF_EL1  + 3200000ULL)
#define OF_EL2   (OF_ER1  + 3200000ULL)            // N*4
#define OF_ER2   (OF_EL2  + 400000ULL)
#define OF_DEG   (OF_ER2  + 400000ULL)             // N*4
#define OF_OFFS  (OF_DEG  + 400000ULL)             // (N+1)*4 padded
#define OF_CUR   (OF_OFFS + 400128ULL)             // N*4
#define OF_SRCC  (OF_CUR  + 400000ULL)             // E*4
#define OF_BSUM  (OF_SRCC + 6800000ULL)            // 2048
#define OF_BOFF  (OF_BSUM + 2048ULL)               // 2048
#define OF_PRM   (OF_BOFF + 2048ULL)               // params block (~136B)

// params block: [0..7] minkey1(u32), [8] minkey2(u32), [16..23] pe1, [24..31] ipe1, [32] pe2, [33] ipe2

typedef _Float16 f16x8 __attribute__((ext_vector_type(8)));
typedef _Float16 f16x4 __attribute__((ext_vector_type(4)));
typedef float f32x4 __attribute__((ext_vector_type(4)));

__device__ __forceinline__ unsigned f2key(float f){
  unsigned u = __float_as_uint(f);
  return (u & 0x80000000u) ? ~u : (u | 0x80000000u);
}
__device__ __forceinline__ float key2f(unsigned k){
  unsigned u = (k & 0x80000000u) ? (k & 0x7FFFFFFFu) : ~k;
  return __uint_as_float(u);
}
__device__ __forceinline__ unsigned short f2b(float f){  // f32 -> bf16 RNE
  unsigned u = __float_as_uint(f);
  unsigned r = u + 0x7FFFu + ((u >> 16) & 1u);
  return (unsigned short)(r >> 16);
}
__device__ __forceinline__ float b2f(unsigned short b){
  return __uint_as_float(((unsigned)b) << 16);
}
__device__ __forceinline__ unsigned pk2(float lo, float hi){
  return (unsigned)f2b(lo) | ((unsigned)f2b(hi) << 16);
}
__device__ __forceinline__ float leaky(float e){ return e >= 0.f ? e : 0.2f*e; }

// ---------------- init ----------------
__global__ void k_init(const float* __restrict__ p1, const float* __restrict__ p2, unsigned* __restrict__ prm){
  int t = threadIdx.x;
  float* prf = (float*)prm;
  if (t < 8){
    prm[t] = 0xFFFFFFFFu;
    float pe = 1.f/(1.f + __expf(-p1[t])) + 1.0f;
    prf[16 + t] = pe;
    prf[24 + t] = 1.f/pe;
  }
  if (t == 0){
    prm[8] = 0xFFFFFFFFu;
    float pe = 1.f/(1.f + __expf(-p2[0])) + 1.0f;
    prf[32] = pe;
    prf[33] = 1.f/pe;
  }
}

__global__ void k_zero_deg(int* __restrict__ deg){
  int i = blockIdx.x*256 + threadIdx.x;
  if (i < NN) deg[i] = 0;
}

// ---------------- GEMM1 (MFMA fp16): ft1 = x @ W1^T (bf16 out) + per-head min ----------------
// grid: (C1/BN, ceil(NN/BM)); block 256 = 4 waves (2x2), each wave -> 64x64 output
#define G1_BM 128
#define G1_BN 128
#define G1_BK 64
#define G1_LDK 72   // padded LDS K-stride (stride 144B = 36 dwords -> 2-way bank aliasing, free)
__global__ __launch_bounds__(256) void k_gemm1(const float* __restrict__ x, const float* __restrict__ W,
                                               unsigned short* __restrict__ ft1b, unsigned* __restrict__ prm){
  __shared__ _Float16 As[G1_BM][G1_LDK];
  __shared__ _Float16 Bs[G1_BN][G1_LDK];
  int t = threadIdx.x;
  int lane = t & 63, w = t >> 6;
  int wr = w >> 1, wc = w & 1;
  int ct = blockIdx.x * G1_BN;
  int rt = blockIdx.y * G1_BM;

  f32x4 zero = {0.f,0.f,0.f,0.f};
  f32x4 acc[4][4];
  #pragma unroll
  for (int m=0;m<4;m++)
    #pragma unroll
    for (int n=0;n<4;n++) acc[m][n] = zero;

  for (int kt = 0; kt < F1; kt += G1_BK){
    // stage A: 128 rows x 64 k (f32 -> f16), 2048 float4 total, 8 per thread
    #pragma unroll
    for (int i = 0; i < 8; i++){
      int idx = i*256 + t;
      int row = idx >> 4, c4 = (idx & 15) << 2;
      int gr = rt + row;
      float4 v = make_float4(0.f,0.f,0.f,0.f);
      if (gr < NN) v = *(const float4*)&x[(size_t)gr*F1 + kt + c4];
      f16x4 hv = { (_Float16)v.x, (_Float16)v.y, (_Float16)v.z, (_Float16)v.w };
      *(f16x4*)&As[row][c4] = hv;
    }
    // stage B: W rows ct..ct+127 (always < 512, no guard)
    #pragma unroll
    for (int i = 0; i < 8; i++){
      int idx = i*256 + t;
      int row = idx >> 4, c4 = (idx & 15) << 2;
      float4 v = *(const float4*)&W[(size_t)(ct+row)*F1 + kt + c4];
      f16x4 hv = { (_Float16)v.x, (_Float16)v.y, (_Float16)v.z, (_Float16)v.w };
      *(f16x4*)&Bs[row][c4] = hv;
    }
    __syncthreads();
    #pragma unroll
    for (int kk = 0; kk < 2; kk++){
      int kb = kk*32 + (lane >> 4)*8;
      int ar = wr*64 + (lane & 15);
      int bc = wc*64 + (lane & 15);
      f16x8 af[4], bf[4];
      #pragma unroll
      for (int m=0;m<4;m++) af[m] = *(f16x8*)&As[ar + m*16][kb];
      #pragma unroll
      for (int n=0;n<4;n++) bf[n] = *(f16x8*)&Bs[bc + n*16][kb];
      #pragma unroll
      for (int m=0;m<4;m++)
        #pragma unroll
        for (int n=0;n<4;n++)
          acc[m][n] = __builtin_amdgcn_mfma_f32_16x16x32_f16(af[m], bf[n], acc[m][n], 0, 0, 0);
    }
    __syncthreads();
  }

  // epilogue: D mapping col=lane&15, row=(lane>>4)*4+j ; each wave spans ONE head
  int h = (ct >> 6) + wc;
  unsigned kmin = 0xFFFFFFFFu;
  #pragma unroll
  for (int m=0;m<4;m++){
    #pragma unroll
    for (int n=0;n<4;n++){
      int col = ct + wc*64 + n*16 + (lane & 15);
      int rbase = rt + wr*64 + m*16 + (lane >> 4)*4;
      #pragma unroll
      for (int j=0;j<4;j++){
        int row = rbase + j;
        if (row < NN){
          unsigned short ub = f2b(acc[m][n][j]);
          ft1b[(size_t)row*C1 + col] = ub;
          kmin = min(kmin, f2key(b2f(ub)));
        }
      }
    }
  }
  #pragma unroll
  for (int off=1; off<64; off<<=1) kmin = min(kmin, (unsigned)__shfl_xor((int)kmin, off));
  if (lane == 0) atomicMin(&prm[h], kmin);
}

// ---------------- CSR build ----------------
__global__ void k_count(const int* __restrict__ dst, int* __restrict__ deg){
  int e = blockIdx.x*256 + threadIdx.x;
  if (e < EE) atomicAdd(&deg[dst[e]], 1);
}
__global__ void k_scan1(const int* __restrict__ deg, int* __restrict__ offs, int* __restrict__ bsum){
  __shared__ int s[256];
  int t = threadIdx.x; int i = blockIdx.x*256 + t;
  int v = (i < NN) ? deg[i] : 0;
  s[t] = v; __syncthreads();
  for (int off=1; off<256; off<<=1){
    int tmp = (t>=off) ? s[t-off] : 0;
    __syncthreads(); s[t] += tmp; __syncthreads();
  }
  if (i < NN) offs[i] = s[t] - v;
  if (t == 255) bsum[blockIdx.x] = s[255];
}
__global__ void k_scan2(int* __restrict__ bsum, int* __restrict__ boff, int nb){
  __shared__ int s[512];
  int t = threadIdx.x;
  int v = (t < nb) ? bsum[t] : 0;
  s[t] = v; __syncthreads();
  for (int off=1; off<512; off<<=1){
    int tmp = (t>=off) ? s[t-off] : 0;
    __syncthreads(); s[t] += tmp; __syncthreads();
  }
  if (t < nb) boff[t] = s[t] - v;
}
__global__ void k_scan3(int* __restrict__ offs, int* __restrict__ cur, const int* __restrict__ boff){
  int i = blockIdx.x*256 + threadIdx.x;
  if (i < NN){
    int v = offs[i] + boff[blockIdx.x];
    offs[i] = v; cur[i] = v;
  }
  if (i == 0) offs[NN] = EE;
}
__global__ void k_fill(const int* __restrict__ src, const int* __restrict__ dst,
                       int* __restrict__ cur, int* __restrict__ srcc){
  int e = blockIdx.x*256 + threadIdx.x;
  if (e < EE){
    int d = dst[e];
    int pos = atomicAdd(&cur[d], 1);
    srcc[pos] = src[e];
  }
}

// ---------------- transform1: el1/er1 + pf1 (in place, bf16) ----------------
__global__ __launch_bounds__(256) void k_transform1(unsigned short* __restrict__ ft1b,
    const float* __restrict__ al1, const float* __restrict__ ar1,
    float* __restrict__ el1, float* __restrict__ er1, const unsigned* __restrict__ prm){
  int lane = threadIdx.x & 63; int w = threadIdx.x >> 6;
  int n = blockIdx.x*4 + w;
  if (n >= NN) return;
  const float* prf = (const float*)prm;
  float vv[8], elp[8], erp[8];
  #pragma unroll
  for (int h=0; h<8; h++){
    vv[h]  = b2f(ft1b[(size_t)n*C1 + h*HF + lane]);
    elp[h] = vv[h]*al1[h*HF + lane];
    erp[h] = vv[h]*ar1[h*HF + lane];
  }
  #pragma unroll
  for (int h=0; h<8; h++){
    #pragma unroll
    for (int off=1; off<64; off<<=1){
      elp[h] += __shfl_xor(elp[h], off);
      erp[h] += __shfl_xor(erp[h], off);
    }
  }
  if (lane == 0){
    #pragma unroll
    for (int h=0; h<8; h++){ el1[(size_t)n*8+h]=elp[h]; er1[(size_t)n*8+h]=erp[h]; }
  }
  #pragma unroll
  for (int h=0; h<8; h++){
    float mu = key2f(prm[h]);
    float pe = prf[16+h];
    float base = vv[h] - mu + EPS;   // >= EPS since mu is min over rounded values
    ft1b[(size_t)n*C1 + h*HF + lane] = f2b(__expf(pe * __logf(base)));
  }
}

// ---------------- layer-1 fused attention + aggregation + elu (bf16 tables) ----------------
__global__ __launch_bounds__(256) void k_agg1(const unsigned short* __restrict__ pf1b,
    const float* __restrict__ el1, const float* __restrict__ er1,
    const int* __restrict__ offs, const int* __restrict__ srcc,
    const float* __restrict__ b1, const unsigned* __restrict__ prm,
    unsigned short* __restrict__ hcatb){
  int lane = threadIdx.x & 63; int w = threadIdx.x >> 6;
  int v = blockIdx.x*4 + w;
  if (v >= NN) return;
  const float* prf = (const float*)prm;
  int h = lane >> 3;
  int s = lane & 7;
  int f0 = (lane & 7)*8;
  int start = offs[v], end = offs[v+1];
  float erh = er1[(size_t)v*8 + h];

  float m = -INFINITY;
  for (int pos = start + s; pos < end; pos += 8){
    int u = srcc[pos];
    float e = leaky(el1[(size_t)u*8 + h] + erh);
    m = fmaxf(m, e);
  }
  m = fmaxf(m, __shfl_xor(m,1)); m = fmaxf(m, __shfl_xor(m,2)); m = fmaxf(m, __shfl_xor(m,4));
  float S = 0.f;
  for (int pos = start + s; pos < end; pos += 8){
    int u = srcc[pos];
    float e = leaky(el1[(size_t)u*8 + h] + erh);
    S += __expf(e - m);
  }
  S += __shfl_xor(S,1); S += __shfl_xor(S,2); S += __shfl_xor(S,4);
  float invS = 1.f / S;

  float acc[8];
  #pragma unroll
  for (int j=0;j<8;j++) acc[j]=0.f;
  for (int pos = start; pos < end; ++pos){
    int u = srcc[pos];
    float e = leaky(el1[(size_t)u*8 + h] + erh);
    float a = __expf(e - m) * invS;
    uint4 q = *(const uint4*)&pf1b[(size_t)u*C1 + h*HF + f0];
    acc[0] += a*b2f((unsigned short)(q.x & 0xFFFFu));
    acc[1] += a*b2f((unsigned short)(q.x >> 16));
    acc[2] += a*b2f((unsigned short)(q.y & 0xFFFFu));
    acc[3] += a*b2f((unsigned short)(q.y >> 16));
    acc[4] += a*b2f((unsigned short)(q.z & 0xFFFFu));
    acc[5] += a*b2f((unsigned short)(q.z >> 16));
    acc[6] += a*b2f((unsigned short)(q.w & 0xFFFFu));
    acc[7] += a*b2f((unsigned short)(q.w >> 16));
  }

  float mu = key2f(prm[h]);
  float ipe = prf[24+h];
  float y[8];
  #pragma unroll
  for (int j=0;j<8;j++){
    float r = __expf(ipe * __logf(acc[j] + EPS)) + mu + b1[h*HF + f0 + j];
    y[j] = (r > 0.f) ? r : (__expf(r) - 1.f);
  }
  uint4 o;
  o.x = pk2(y[0],y[1]); o.y = pk2(y[2],y[3]); o.z = pk2(y[4],y[5]); o.w = pk2(y[6],y[7]);
  *(uint4*)&hcatb[(size_t)v*C1 + h*HF + f0] = o;
}

// ---------------- GEMM2: ft2 = hcat @ W2^T (f32 out), + el2/er2 + global min ----------------
#define G2_BM 64
#define G2_BK 64
__global__ __launch_bounds__(256) void k_gemm2(const unsigned short* __restrict__ hcatb, const float* __restrict__ W2,
    float* __restrict__ ft2, float* __restrict__ el2, float* __restrict__ er2,
    const float* __restrict__ al2, const float* __restrict__ ar2, unsigned* __restrict__ prm){
  __shared__ float As[G2_BK][G2_BM];
  __shared__ float Bs[G2_BK][C2];
  __shared__ float els[64], ers[64];
  __shared__ unsigned mk;
  int t = threadIdx.x;
  int tx = t & 7, ty = t >> 3;
  int rt = blockIdx.x * G2_BM;
  float acc[2][5];
  #pragma unroll
  for (int i=0;i<2;i++)
    #pragma unroll
    for (int j=0;j<5;j++) acc[i][j]=0.f;

  for (int k0=0; k0<C1; k0+=G2_BK){
    #pragma unroll
    for (int i=0;i<2;i++){
      int id = t*2 + i;                 // 0..511
      int row = id >> 3; int c8 = (id & 7)*8;
      int gr = rt + row;
      uint4 q = make_uint4(0,0,0,0);
      if (gr < NN) q = *(const uint4*)&hcatb[(size_t)gr*C1 + k0 + c8];
      As[c8+0][row]=b2f((unsigned short)(q.x & 0xFFFFu));
      As[c8+1][row]=b2f((unsigned short)(q.x >> 16));
      As[c8+2][row]=b2f((unsigned short)(q.y & 0xFFFFu));
      As[c8+3][row]=b2f((unsigned short)(q.y >> 16));
      As[c8+4][row]=b2f((unsigned short)(q.z & 0xFFFFu));
      As[c8+5][row]=b2f((unsigned short)(q.z >> 16));
      As[c8+6][row]=b2f((unsigned short)(q.w & 0xFFFFu));
      As[c8+7][row]=b2f((unsigned short)(q.w >> 16));
    }
    #pragma unroll
    for (int i=0;i<10;i++){
      int id = t + i*256;
      int c = id >> 6, kk = id & 63;
      Bs[kk][c] = W2[(size_t)c*C1 + k0 + kk];
    }
    __syncthreads();
    #pragma unroll
    for (int kk=0; kk<G2_BK; ++kk){
      float2 a = *(float2*)&As[kk][ty*2];
      float b0=Bs[kk][tx*5+0], b1v=Bs[kk][tx*5+1], b2v=Bs[kk][tx*5+2], b3v=Bs[kk][tx*5+3], b4v=Bs[kk][tx*5+4];
      acc[0][0]+=a.x*b0; acc[0][1]+=a.x*b1v; acc[0][2]+=a.x*b2v; acc[0][3]+=a.x*b3v; acc[0][4]+=a.x*b4v;
      acc[1][0]+=a.y*b0; acc[1][1]+=a.y*b1v; acc[1][2]+=a.y*b2v; acc[1][3]+=a.y*b3v; acc[1][4]+=a.y*b4v;
    }
    __syncthreads();
  }

  if (t < 64){ els[t]=0.f; ers[t]=0.f; }
  if (t == 0) mk = 0xFFFFFFFFu;
  __syncthreads();
  unsigned kmin = 0xFFFFFFFFu;
  #pragma unroll
  for (int i=0;i<2;i++){
    int r = rt + ty*2 + i;
    if (r < NN){
      float elp=0.f, erp=0.f;
      #pragma unroll
      for (int j=0;j<5;j++){
        float vv = acc[i][j]; int c = tx*5+j;
        ft2[(size_t)r*C2 + c] = vv;
        elp += vv*al2[c]; erp += vv*ar2[c];
        kmin = min(kmin, f2key(vv));
      }
      atomicAdd(&els[ty*2+i], elp);
      atomicAdd(&ers[ty*2+i], erp);
    }
  }
  atomicMin(&mk, kmin);
  __syncthreads();
  if (t < 64 && rt + t < NN){ el2[rt+t]=els[t]; er2[rt+t]=ers[t]; }
  if (t == 0) atomicMin(&prm[8], mk);
}

// ---------------- transform2: pf2 in place (f32) ----------------
__global__ void k_transform2(float* __restrict__ ft2, const unsigned* __restrict__ prm){
  int i = blockIdx.x*256 + threadIdx.x;
  if (i >= NN*C2) return;
  const float* prf = (const float*)prm;
  float mu = key2f(prm[8]);
  float pe = prf[32];
  float v = ft2[i];
  ft2[i] = __expf(pe * __logf(v - mu + EPS));
}

// ---------------- layer-2 fused attention + aggregation + log_softmax ----------------
__global__ __launch_bounds__(256) void k_agg2(const float* __restrict__ pf2,
    const float* __restrict__ el2, const float* __restrict__ er2,
    const int* __restrict__ offs, const int* __restrict__ srcc,
    const float* __restrict__ b2, const unsigned* __restrict__ prm,
    float* __restrict__ out){
  int lane = threadIdx.x & 63; int w = threadIdx.x >> 6;
  int v = blockIdx.x*4 + w;
  if (v >= NN) return;
  const float* prf = (const float*)prm;
  int start = offs[v], end = offs[v+1];
  float erv = er2[v];

  float m = -INFINITY;
  for (int pos = start + lane; pos < end; pos += 64){
    float e = leaky(el2[srcc[pos]] + erv);
    m = fmaxf(m, e);
  }
  #pragma unroll
  for (int off=1; off<64; off<<=1) m = fmaxf(m, __shfl_xor(m, off));
  float S = 0.f;
  for (int pos = start + lane; pos < end; pos += 64){
    float e = leaky(el2[srcc[pos]] + erv);
    S += __expf(e - m);
  }
  #pragma unroll
  for (int off=1; off<64; off<<=1) S += __shfl_xor(S, off);
  float invS = 1.f / S;

  float acc = 0.f;
  for (int pos = start; pos < end; ++pos){
    int u = srcc[pos];
    float e = leaky(el2[u] + erv);
    float a = __expf(e - m) * invS;
    if (lane < C2) acc += a * pf2[(size_t)u*C2 + lane];
  }

  float y;
  if (lane < C2){
    float mu = key2f(prm[8]);
    y = __expf(prf[33] * __logf(acc + EPS)) + mu + b2[lane];
  } else {
    y = -INFINITY;
  }
  float mx = y;
  #pragma unroll
  for (int off=1; off<64; off<<=1) mx = fmaxf(mx, __shfl_xor(mx, off));
  float se = (lane < C2) ? __expf(y - mx) : 0.f;
  #pragma unroll
  for (int off=1; off<64; off<<=1) se += __shfl_xor(se, off);
  if (lane < C2) out[(size_t)v*C2 + lane] = y - mx - __logf(se);
}

// ---------------- host ----------------
extern "C" void kernel_launch(void* const* d_in, const int* in_sizes, int n_in,
                              void* d_out, int out_size, void* d_ws, size_t ws_size,
                              hipStream_t stream){
  const float* x   = (const float*)d_in[0];
  const int*   src = (const int*)d_in[1];
  const int*   dst = (const int*)d_in[2];
  const float* W1  = (const float*)d_in[3];
  const float* al1 = (const float*)d_in[4];
  const float* ar1 = (const float*)d_in[5];
  const float* b1  = (const float*)d_in[6];
  const float* p1  = (const float*)d_in[7];
  const float* W2  = (const float*)d_in[8];
  const float* al2 = (const float*)d_in[9];
  const float* ar2 = (const float*)d_in[10];
  const float* b2  = (const float*)d_in[11];
  const float* p2  = (const float*)d_in[12];
  float* out = (float*)d_out;
  char* ws = (char*)d_ws;

  unsigned short* pf1b  = (unsigned short*)(ws + OF_PF1);
  unsigned short* hcatb = (unsigned short*)(ws + OF_HCAT);
  float* ft2   = (float*)(ws + OF_FT2);
  float* el1   = (float*)(ws + OF_EL1);
  float* er1   = (float*)(ws + OF_ER1);
  float* el2   = (float*)(ws + OF_EL2);
  float* er2   = (float*)(ws + OF_ER2);
  int*   deg   = (int*)(ws + OF_DEG);
  int*   offs  = (int*)(ws + OF_OFFS);
  int*   cur   = (int*)(ws + OF_CUR);
  int*   srcc  = (int*)(ws + OF_SRCC);
  int*   bsum  = (int*)(ws + OF_BSUM);
  int*   boff  = (int*)(ws + OF_BOFF);
  unsigned* prm = (unsigned*)(ws + OF_PRM);

  const int NB1 = (NN + 255)/256;
  const int NBE = (EE + 255)/256;

  k_init<<<1, 64, 0, stream>>>(p1, p2, prm);
  k_zero_deg<<<NB1, 256, 0, stream>>>(deg);
  k_gemm1<<<dim3(C1/G1_BN, (NN + G1_BM - 1)/G1_BM), 256, 0, stream>>>(x, W1, pf1b, prm);
  k_count<<<NBE, 256, 0, stream>>>(dst, deg);
  k_scan1<<<NB1, 256, 0, stream>>>(deg, offs, bsum);
  k_scan2<<<1, 512, 0, stream>>>(bsum, boff, NB1);
  k_scan3<<<NB1, 256, 0, stream>>>(offs, cur, boff);
  k_fill<<<NBE, 256, 0, stream>>>(src, dst, cur, srcc);
  k_transform1<<<NN/4, 256, 0, stream>>>(pf1b, al1, ar1, el1, er1, prm);
  k_agg1<<<NN/4, 256, 0, stream>>>(pf1b, el1, er1, offs, srcc, b1, prm, hcatb);
  k_gemm2<<<(NN + G2_BM - 1)/G2_BM, 256, 0, stream>>>(hcatb, W2, ft2, el2, er2, al2, ar2, prm);
  k_transform2<<<(NN*C2 + 255)/256, 256, 0, stream>>>(ft2, prm);
  k_agg2<<<NN/4, 256, 0, stream>>>(ft2, el2, er2, offs, srcc, b2, prm, out);
}